// Round 1
// baseline (522.314 us; speedup 1.0000x reference)
//
#include <hip/hip_runtime.h>
#include <hip/hip_bf16.h>

// Problem dims (fixed by reference):
//   x: (512, 4096) f32, Pi/Pi2: (4096,4096) f32
//   indices_packed: (4096, 2048) i32 (byte values, 2 nibbles = 2 weights)
//   weight_norms: (4096, 32) f32, codebook: (16,) f32  (x2 passes)
//   out: (512, 4096) f32
// Decomposition:
//   Y (512x8192 bf16, in d_ws) = x @ [Pi; Pi2]^T      (NT gemm, K=4096)
//   out = Y @ Wcat^T                                   (NT gemm, K=8192, W dequant on the fly)

typedef __bf16 bf16x8 __attribute__((ext_vector_type(8)));
typedef __bf16 bf16x4 __attribute__((ext_vector_type(4)));
typedef float  f32x4  __attribute__((ext_vector_type(4)));

#define T_DIM   512
#define N_DIM   4096
#define M_DIM   4096
#define K2_DIM  8192
#define INV_SQRT_G 0.08838834764831843f   // 1/sqrt(128)

// LDS tile: 64 rows x 64 bf16 (128 B/row). XOR-swizzle byte offset with
// (row&7)<<4 to spread the stride-128B fragment reads across banks (G4).
__device__ __forceinline__ int lds_elem(int row, int kByte) {
    return row * 64 + ((kByte ^ ((row & 7) << 4)) >> 1);
}

// ---------------------------------------------------------------------------
// GEMM1: Y[t, n] = sum_k x[t,k] * PiCat[n,k];  PiCat rows 0..4095 = Pi, rest Pi2
// ---------------------------------------------------------------------------
__global__ __launch_bounds__(256) void gemm1_kernel(
    const float* __restrict__ x, const float* __restrict__ Pi,
    const float* __restrict__ Pi2, __bf16* __restrict__ Y)
{
    __shared__ __bf16 sA[64 * 64];
    __shared__ __bf16 sB[64 * 64];

    const int tid = threadIdx.x;
    const int n0  = blockIdx.x * 64;   // output column tile (rotation row)
    const int t0  = blockIdx.y * 64;   // token tile

    const float* Bsrc = (n0 < N_DIM) ? Pi : Pi2;
    const int nloc = n0 & (N_DIM - 1);

    const int wid  = tid >> 6;
    const int lane = tid & 63;
    const int wr = (wid >> 1) * 32;    // wave row base in tile
    const int wc = (wid & 1) * 32;     // wave col base in tile
    const int lr = lane & 15;
    const int lg = lane >> 4;

    f32x4 acc[2][2] = {};

    for (int k0 = 0; k0 < N_DIM; k0 += 64) {
        // ---- stage A (x) and B (Pi/Pi2): fp32 -> bf16 into swizzled LDS
        #pragma unroll
        for (int it = 0; it < 4; ++it) {
            int flat = it * 256 + tid;       // float4 index within 64x64 tile
            int row  = flat >> 4;            // 16 float4 per row
            int kq   = (flat & 15) << 2;     // k offset in floats

            float4 fa = *reinterpret_cast<const float4*>(
                &x[(size_t)(t0 + row) * N_DIM + k0 + kq]);
            bf16x4 ha = { (__bf16)fa.x, (__bf16)fa.y, (__bf16)fa.z, (__bf16)fa.w };
            *reinterpret_cast<bf16x4*>(&sA[lds_elem(row, kq << 1)]) = ha;

            float4 fb = *reinterpret_cast<const float4*>(
                &Bsrc[(size_t)(nloc + row) * N_DIM + k0 + kq]);
            bf16x4 hb = { (__bf16)fb.x, (__bf16)fb.y, (__bf16)fb.z, (__bf16)fb.w };
            *reinterpret_cast<bf16x4*>(&sB[lds_elem(row, kq << 1)]) = hb;
        }
        __syncthreads();

        // ---- MFMA: each wave computes 32x32 = 2x2 fragments of 16x16
        #pragma unroll
        for (int kh = 0; kh < 2; ++kh) {
            const int kB = kh * 64 + lg * 16;
            bf16x8 a0 = *reinterpret_cast<const bf16x8*>(&sA[lds_elem(wr + lr,      kB)]);
            bf16x8 a1 = *reinterpret_cast<const bf16x8*>(&sA[lds_elem(wr + 16 + lr, kB)]);
            bf16x8 b0 = *reinterpret_cast<const bf16x8*>(&sB[lds_elem(wc + lr,      kB)]);
            bf16x8 b1 = *reinterpret_cast<const bf16x8*>(&sB[lds_elem(wc + 16 + lr, kB)]);
            acc[0][0] = __builtin_amdgcn_mfma_f32_16x16x32_bf16(a0, b0, acc[0][0], 0, 0, 0);
            acc[0][1] = __builtin_amdgcn_mfma_f32_16x16x32_bf16(a0, b1, acc[0][1], 0, 0, 0);
            acc[1][0] = __builtin_amdgcn_mfma_f32_16x16x32_bf16(a1, b0, acc[1][0], 0, 0, 0);
            acc[1][1] = __builtin_amdgcn_mfma_f32_16x16x32_bf16(a1, b1, acc[1][1], 0, 0, 0);
        }
        __syncthreads();
    }

    // ---- epilogue: C/D layout col=lane&15, row=(lane>>4)*4+e  [m89/m91]
    #pragma unroll
    for (int fi = 0; fi < 2; ++fi)
        #pragma unroll
        for (int fj = 0; fj < 2; ++fj)
            #pragma unroll
            for (int e = 0; e < 4; ++e) {
                int row = t0 + wr + fi * 16 + lg * 4 + e;
                int col = n0 + wc + fj * 16 + lr;
                Y[(size_t)row * K2_DIM + col] = (__bf16)acc[fi][fj][e];
            }
}

// ---------------------------------------------------------------------------
// GEMM2: out[t, m] = sum_j Y[t,j] * Wcat[m,j]; W dequantized on the fly
// ---------------------------------------------------------------------------
__global__ __launch_bounds__(256) void gemm2_kernel(
    const __bf16* __restrict__ Y,
    const int*   __restrict__ idx1, const float* __restrict__ wn1,
    const float* __restrict__ cb1,
    const int*   __restrict__ idx2, const float* __restrict__ wn2,
    const float* __restrict__ cb2,
    float* __restrict__ out)
{
    __shared__ __bf16 sA[64 * 64];
    __shared__ __bf16 sB[64 * 64];
    __shared__ float  cbs[32];

    const int tid = threadIdx.x;
    const int m0  = blockIdx.x * 64;   // output column tile (weight row)
    const int t0  = blockIdx.y * 64;   // token tile

    if (tid < 32) cbs[tid] = (tid < 16) ? cb1[tid] : cb2[tid - 16];
    __syncthreads();

    const int wid  = tid >> 6;
    const int lane = tid & 63;
    const int wr = (wid >> 1) * 32;
    const int wc = (wid & 1) * 32;
    const int lr = lane & 15;
    const int lg = lane >> 4;

    // dequant staging role: 4 threads per weight row, 8 int32 each
    const int dr = tid >> 2;           // row 0..63 within tile
    const int dq = tid & 3;            // quarter of the 32 int32s

    f32x4 acc[2][2] = {};

    for (int k0 = 0; k0 < K2_DIM; k0 += 64) {
        const int   pass = (k0 >= N_DIM);
        const int*  idxp = pass ? idx2 : idx1;
        const float* wn  = pass ? wn2  : wn1;
        const float* cbL = &cbs[pass << 4];
        const int   jloc = k0 & (N_DIM - 1);

        // ---- stage A from Y (bf16, 16B loads): 2 iterations of 256x8 elems
        #pragma unroll
        for (int it = 0; it < 2; ++it) {
            int flat = it * 256 + tid;
            int row  = flat >> 3;        // 8 blocks of 8 per row
            int kb   = (flat & 7) << 3;  // k offset in elems
            bf16x8 v = *reinterpret_cast<const bf16x8*>(
                &Y[(size_t)(t0 + row) * K2_DIM + k0 + kb]);
            *reinterpret_cast<bf16x8*>(&sA[lds_elem(row, kb << 1)]) = v;
        }

        // ---- stage B: dequant 64 rows x 32 int32 (each int32 -> 2 bf16)
        {
            const float s = wn[(size_t)(m0 + dr) * 32 + (jloc >> 7)] * INV_SQRT_G;
            const int* src = idxp + (size_t)(m0 + dr) * (N_DIM / 2) + (jloc >> 1) + dq * 8;
            #pragma unroll
            for (int h = 0; h < 2; ++h) {
                int4 v = *reinterpret_cast<const int4*>(src + h * 4);
                bf16x8 w;
                w[0] = (__bf16)(cbL[v.x & 15] * s);  w[1] = (__bf16)(cbL[(v.x >> 4) & 15] * s);
                w[2] = (__bf16)(cbL[v.y & 15] * s);  w[3] = (__bf16)(cbL[(v.y >> 4) & 15] * s);
                w[4] = (__bf16)(cbL[v.z & 15] * s);  w[5] = (__bf16)(cbL[(v.z >> 4) & 15] * s);
                w[6] = (__bf16)(cbL[v.w & 15] * s);  w[7] = (__bf16)(cbL[(v.w >> 4) & 15] * s);
                *reinterpret_cast<bf16x8*>(&sB[lds_elem(dr, dq * 32 + h * 16)]) = w;
            }
        }
        __syncthreads();

        #pragma unroll
        for (int kh = 0; kh < 2; ++kh) {
            const int kB = kh * 64 + lg * 16;
            bf16x8 a0 = *reinterpret_cast<const bf16x8*>(&sA[lds_elem(wr + lr,      kB)]);
            bf16x8 a1 = *reinterpret_cast<const bf16x8*>(&sA[lds_elem(wr + 16 + lr, kB)]);
            bf16x8 b0 = *reinterpret_cast<const bf16x8*>(&sB[lds_elem(wc + lr,      kB)]);
            bf16x8 b1 = *reinterpret_cast<const bf16x8*>(&sB[lds_elem(wc + 16 + lr, kB)]);
            acc[0][0] = __builtin_amdgcn_mfma_f32_16x16x32_bf16(a0, b0, acc[0][0], 0, 0, 0);
            acc[0][1] = __builtin_amdgcn_mfma_f32_16x16x32_bf16(a0, b1, acc[0][1], 0, 0, 0);
            acc[1][0] = __builtin_amdgcn_mfma_f32_16x16x32_bf16(a1, b0, acc[1][0], 0, 0, 0);
            acc[1][1] = __builtin_amdgcn_mfma_f32_16x16x32_bf16(a1, b1, acc[1][1], 0, 0, 0);
        }
        __syncthreads();
    }

    #pragma unroll
    for (int fi = 0; fi < 2; ++fi)
        #pragma unroll
        for (int fj = 0; fj < 2; ++fj)
            #pragma unroll
            for (int e = 0; e < 4; ++e) {
                int row = t0 + wr + fi * 16 + lg * 4 + e;
                int col = m0 + wc + fj * 16 + lr;
                out[(size_t)row * M_DIM + col] = acc[fi][fj][e];
            }
}

// ---------------------------------------------------------------------------
extern "C" void kernel_launch(void* const* d_in, const int* in_sizes, int n_in,
                              void* d_out, int out_size, void* d_ws, size_t ws_size,
                              hipStream_t stream) {
    const float* x    = (const float*)d_in[0];
    const float* Pi   = (const float*)d_in[1];
    const int*   idx1 = (const int*)  d_in[2];
    const float* wn1  = (const float*)d_in[3];
    const float* cb1  = (const float*)d_in[4];
    const int*   idx2 = (const int*)  d_in[5];
    const float* wn2  = (const float*)d_in[6];
    const float* cb2  = (const float*)d_in[7];
    const float* Pi2  = (const float*)d_in[8];
    float* out = (float*)d_out;

    // workspace: Y (512 x 8192 bf16) = 8 MB
    __bf16* Y = (__bf16*)d_ws;

    dim3 blk(256);
    gemm1_kernel<<<dim3(K2_DIM / 64, T_DIM / 64), blk, 0, stream>>>(x, Pi, Pi2, Y);
    gemm2_kernel<<<dim3(M_DIM / 64, T_DIM / 64), blk, 0, stream>>>(
        Y, idx1, wn1, cb1, idx2, wn2, cb2, out);
}

// Round 2
// 447.584 us; speedup vs baseline: 1.1670x; 1.1670x over previous
//
#include <hip/hip_runtime.h>
#include <hip/hip_bf16.h>

// Problem dims (fixed by reference):
//   x: (512, 4096) f32, Pi/Pi2: (4096,4096) f32
//   indices_packed: (4096, 2048) i32 (one byte value per int32, 2 nibbles = 2 weights)
//   weight_norms: (4096, 32) f32, codebook: (16,) f32  (x2 passes)
//   out: (512, 4096) f32
// Decomposition:
//   Y (512x8192 bf16, in d_ws) = x @ [Pi; Pi2]^T      (NT gemm, K=4096 per half)
//   out = Y @ Wcat^T  (NT gemm, K=8192 split over 2 passes via blockIdx.z + atomicAdd)

typedef __bf16 bf16x8 __attribute__((ext_vector_type(8)));
typedef __bf16 bf16x4 __attribute__((ext_vector_type(4)));
typedef float  f32x4  __attribute__((ext_vector_type(4)));

#define T_DIM   512
#define N_DIM   4096
#define M_DIM   4096
#define K2_DIM  8192
#define INV_SQRT_G 0.08838834764831843f   // 1/sqrt(128)

// LDS tile: [128 rows][32 bf16] = 64 B/row = 4x 16B units per row.
// Swizzle 16B-unit index with (row>>1)&3: fragment reads (16 consecutive rows,
// fixed unit) then hit 8 distinct bank groups x2 rows = 2-way (free).
__device__ __forceinline__ int u16idx(int row, int c16) {
    return row * 4 + (c16 ^ ((row >> 1) & 3));   // in 16B units
}

// ---------------------------------------------------------------------------
// GEMM1: Y[t, n] = sum_k x[t,k] * PiCat[n,k];  PiCat rows 0..4095 = Pi, rest Pi2
// 128x128 tile, BK=32, 4 waves (2x2), 4x4 frags/wave, double-buffered LDS.
// ---------------------------------------------------------------------------
__global__ __launch_bounds__(256, 2) void gemm1_kernel(
    const float* __restrict__ x, const float* __restrict__ Pi,
    const float* __restrict__ Pi2, __bf16* __restrict__ Y)
{
    __shared__ __bf16 sA[2][128 * 32];
    __shared__ __bf16 sB[2][128 * 32];

    const int tid = threadIdx.x;
    const int n0  = blockIdx.x * 128;  // output column tile (rotation row)
    const int t0  = blockIdx.y * 128;  // token tile

    const float* Bsrc = (n0 < N_DIM) ? Pi : Pi2;
    const int nloc = n0 & (N_DIM - 1);

    const int wid  = tid >> 6;
    const int lane = tid & 63;
    const int wr = (wid >> 1) * 64;    // wave row base in tile
    const int wc = (wid & 1) * 64;     // wave col base in tile
    const int lr = lane & 15;
    const int lg = lane >> 4;

    // staging role: float4 units; 128 rows x 8 units/matrix; 4 rows per thread
    const int srow = tid >> 3;         // rows srow, srow+32, srow+64, srow+96
    const int sq   = tid & 7;          // float4 index within row (8 per row)

    f32x4 acc[4][4] = {};
    float4 ra0, ra1, ra2, ra3, rb0, rb1, rb2, rb3;

    auto load_tile = [&](int k0) {
        const float* ax = &x[(size_t)(t0 + srow) * N_DIM + k0 + sq * 4];
        const float* bx = &Bsrc[(size_t)(nloc + srow) * N_DIM + k0 + sq * 4];
        ra0 = *(const float4*)(ax);
        ra1 = *(const float4*)(ax + 32 * N_DIM);
        ra2 = *(const float4*)(ax + 64 * N_DIM);
        ra3 = *(const float4*)(ax + 96 * N_DIM);
        rb0 = *(const float4*)(bx);
        rb1 = *(const float4*)(bx + 32 * N_DIM);
        rb2 = *(const float4*)(bx + 64 * N_DIM);
        rb3 = *(const float4*)(bx + 96 * N_DIM);
    };
    auto cvt4 = [](float4 f) -> bf16x4 {
        bf16x4 h = { (__bf16)f.x, (__bf16)f.y, (__bf16)f.z, (__bf16)f.w };
        return h;
    };
    auto write_tile = [&](int buf) {
        #pragma unroll
        for (int it = 0; it < 4; ++it) {
            int row = srow + it * 32;
            int off = u16idx(row, sq >> 1) * 8 + (sq & 1) * 4;  // bf16 elem offset
            float4 fa = it == 0 ? ra0 : it == 1 ? ra1 : it == 2 ? ra2 : ra3;
            float4 fb = it == 0 ? rb0 : it == 1 ? rb1 : it == 2 ? rb2 : rb3;
            *(bf16x4*)&sA[buf][off] = cvt4(fa);
            *(bf16x4*)&sB[buf][off] = cvt4(fb);
        }
    };

    load_tile(0);
    write_tile(0);
    __syncthreads();

    int cur = 0;
    const int NK = N_DIM / 32;
    for (int k = 0; k < NK; ++k) {
        if (k + 1 < NK) load_tile((k + 1) * 32);   // issue next-tile loads early

        bf16x8 af[4], bfr[4];
        #pragma unroll
        for (int m = 0; m < 4; ++m)
            af[m] = *(const bf16x8*)&sA[cur][u16idx(wr + m * 16 + lr, lg) * 8];
        #pragma unroll
        for (int n = 0; n < 4; ++n)
            bfr[n] = *(const bf16x8*)&sB[cur][u16idx(wc + n * 16 + lr, lg) * 8];
        #pragma unroll
        for (int m = 0; m < 4; ++m)
            #pragma unroll
            for (int n = 0; n < 4; ++n)
                acc[m][n] = __builtin_amdgcn_mfma_f32_16x16x32_bf16(
                    af[m], bfr[n], acc[m][n], 0, 0, 0);

        if (k + 1 < NK) write_tile(cur ^ 1);       // fill other buffer
        __syncthreads();
        cur ^= 1;
    }

    // epilogue: C/D layout col=lane&15, row=(lane>>4)*4+e  [m89/m91]
    #pragma unroll
    for (int m = 0; m < 4; ++m)
        #pragma unroll
        for (int n = 0; n < 4; ++n)
            #pragma unroll
            for (int e = 0; e < 4; ++e) {
                int row = t0 + wr + m * 16 + lg * 4 + e;
                int col = n0 + wc + n * 16 + lr;
                Y[(size_t)row * K2_DIM + col] = (__bf16)acc[m][n][e];
            }
}

// ---------------------------------------------------------------------------
// GEMM2: out[t, m] += sum_j Y[t, pass*4096+j] * Wpass[m,j]; dequant on the fly.
// Same tile structure; blockIdx.z = pass; accumulate via atomicAdd (out pre-zeroed).
// ---------------------------------------------------------------------------
__global__ __launch_bounds__(256, 2) void gemm2_kernel(
    const __bf16* __restrict__ Y,
    const int*   __restrict__ idx1, const float* __restrict__ wn1,
    const float* __restrict__ cb1,
    const int*   __restrict__ idx2, const float* __restrict__ wn2,
    const float* __restrict__ cb2,
    float* __restrict__ out)
{
    __shared__ __bf16 sA[2][128 * 32];
    __shared__ __bf16 sB[2][128 * 32];
    __shared__ float  cbs[16];

    const int tid  = threadIdx.x;
    const int m0   = blockIdx.x * 128;  // weight-row tile
    const int t0   = blockIdx.y * 128;  // token tile
    const int pass = blockIdx.z;

    const int*   idxp = pass ? idx2 : idx1;
    const float* wn   = pass ? wn2  : wn1;
    const float* cbg  = pass ? cb2  : cb1;

    if (tid < 16) cbs[tid] = cbg[tid] * INV_SQRT_G;
    __syncthreads();

    const int wid  = tid >> 6;
    const int lane = tid & 63;
    const int wr = (wid >> 1) * 64;
    const int wc = (wid & 1) * 64;
    const int lr = lane & 15;
    const int lg = lane >> 4;

    // staging role: 2 threads per row; each covers 16 k-elems (2x 16B units)
    const int srow = tid >> 1;
    const int sh   = tid & 1;

    f32x4 acc[4][4] = {};
    bf16x8 ya0, ya1;
    int4   wi0, wi1;
    float  wscale;

    auto load_tile = [&](int kl) {   // kl = pass-local k offset (0..4095)
        const __bf16* yp = &Y[(size_t)(t0 + srow) * K2_DIM + pass * N_DIM + kl + sh * 16];
        ya0 = *(const bf16x8*)yp;
        ya1 = *(const bf16x8*)(yp + 8);
        const int* ip = &idxp[(size_t)(m0 + srow) * (N_DIM / 2) + (kl >> 1) + sh * 8];
        wi0 = *(const int4*)ip;
        wi1 = *(const int4*)(ip + 4);
        wscale = wn[(size_t)(m0 + srow) * 32 + (kl >> 7)];
    };
    auto dq = [&](int4 v) -> bf16x8 {
        bf16x8 w;
        w[0] = (__bf16)(cbs[v.x & 15] * wscale);  w[1] = (__bf16)(cbs[(v.x >> 4) & 15] * wscale);
        w[2] = (__bf16)(cbs[v.y & 15] * wscale);  w[3] = (__bf16)(cbs[(v.y >> 4) & 15] * wscale);
        w[4] = (__bf16)(cbs[v.z & 15] * wscale);  w[5] = (__bf16)(cbs[(v.z >> 4) & 15] * wscale);
        w[6] = (__bf16)(cbs[v.w & 15] * wscale);  w[7] = (__bf16)(cbs[(v.w >> 4) & 15] * wscale);
        return w;
    };
    auto write_tile = [&](int buf) {
        *(bf16x8*)&sA[buf][u16idx(srow, sh * 2)     * 8] = ya0;
        *(bf16x8*)&sA[buf][u16idx(srow, sh * 2 + 1) * 8] = ya1;
        *(bf16x8*)&sB[buf][u16idx(srow, sh * 2)     * 8] = dq(wi0);
        *(bf16x8*)&sB[buf][u16idx(srow, sh * 2 + 1) * 8] = dq(wi1);
    };

    load_tile(0);
    write_tile(0);
    __syncthreads();

    int cur = 0;
    const int NK = N_DIM / 32;
    for (int k = 0; k < NK; ++k) {
        if (k + 1 < NK) load_tile((k + 1) * 32);

        bf16x8 af[4], bfr[4];
        #pragma unroll
        for (int m = 0; m < 4; ++m)
            af[m] = *(const bf16x8*)&sA[cur][u16idx(wr + m * 16 + lr, lg) * 8];
        #pragma unroll
        for (int n = 0; n < 4; ++n)
            bfr[n] = *(const bf16x8*)&sB[cur][u16idx(wc + n * 16 + lr, lg) * 8];
        #pragma unroll
        for (int m = 0; m < 4; ++m)
            #pragma unroll
            for (int n = 0; n < 4; ++n)
                acc[m][n] = __builtin_amdgcn_mfma_f32_16x16x32_bf16(
                    af[m], bfr[n], acc[m][n], 0, 0, 0);

        if (k + 1 < NK) write_tile(cur ^ 1);
        __syncthreads();
        cur ^= 1;
    }

    #pragma unroll
    for (int m = 0; m < 4; ++m)
        #pragma unroll
        for (int n = 0; n < 4; ++n)
            #pragma unroll
            for (int e = 0; e < 4; ++e) {
                int row = t0 + wr + m * 16 + lg * 4 + e;
                int col = m0 + wc + n * 16 + lr;
                atomicAdd(&out[(size_t)row * M_DIM + col], acc[m][n][e]);
            }
}

// ---------------------------------------------------------------------------
extern "C" void kernel_launch(void* const* d_in, const int* in_sizes, int n_in,
                              void* d_out, int out_size, void* d_ws, size_t ws_size,
                              hipStream_t stream) {
    const float* x    = (const float*)d_in[0];
    const float* Pi   = (const float*)d_in[1];
    const int*   idx1 = (const int*)  d_in[2];
    const float* wn1  = (const float*)d_in[3];
    const float* cb1  = (const float*)d_in[4];
    const int*   idx2 = (const int*)  d_in[5];
    const float* wn2  = (const float*)d_in[6];
    const float* cb2  = (const float*)d_in[7];
    const float* Pi2  = (const float*)d_in[8];
    float* out = (float*)d_out;

    // workspace: Y (512 x 8192 bf16) = 8 MB
    __bf16* Y = (__bf16*)d_ws;

    hipMemsetAsync(d_out, 0, (size_t)T_DIM * M_DIM * sizeof(float), stream);

    dim3 blk(256);
    gemm1_kernel<<<dim3(K2_DIM / 128, T_DIM / 128), blk, 0, stream>>>(x, Pi, Pi2, Y);
    gemm2_kernel<<<dim3(M_DIM / 128, T_DIM / 128, 2), blk, 0, stream>>>(
        Y, idx1, wn1, cb1, idx2, wn2, cb2, out);
}

// Round 3
// 386.849 us; speedup vs baseline: 1.3502x; 1.1570x over previous
//
#include <hip/hip_runtime.h>
#include <hip/hip_bf16.h>

// Decomposition:
//   xb (512x4096 bf16, ws+0)      = cvt(x)
//   Y  (512x8192 bf16, ws+4MB)    = x @ [Pi; Pi2]^T   (NT gemm, fp32 B cvt on the fly)
//   out (512x4096 f32)           += Y @ Wpass^T       (per pass z=0,1; dequant B on the fly)
// Tiles: 128 (rows=tokens) x 64 (cols), BK=64, 4 waves (2x2), wave tile 64x32,
// acc 4x2 frags, double-buffered LDS, A staged via global_load_lds(16B).

typedef __bf16 bf16x8 __attribute__((ext_vector_type(8)));
typedef float  f32x4  __attribute__((ext_vector_type(4)));

#define T_DIM   512
#define N_DIM   4096
#define M_DIM   4096
#define K2_DIM  8192
#define INV_SQRT_G 0.08838834764831843f   // 1/sqrt(128)

typedef const __attribute__((address_space(1))) unsigned int as1_u32;
typedef __attribute__((address_space(3)))       unsigned int as3_u32;

__device__ __forceinline__ void gload16(const void* g, void* l) {
    // per-lane global src; LDS dst = wave-uniform base + lane*16 (m104)
    __builtin_amdgcn_global_load_lds((as1_u32*)g, (as3_u32*)l, 16, 0, 0);
}

// ---------------------------------------------------------------------------
__global__ __launch_bounds__(256) void cvt_x_kernel(
    const float* __restrict__ x, __bf16* __restrict__ xb)
{
    int i = (blockIdx.x * 256 + threadIdx.x) * 8;
    float4 f0 = *(const float4*)&x[i];
    float4 f1 = *(const float4*)&x[i + 4];
    bf16x8 h = { (__bf16)f0.x, (__bf16)f0.y, (__bf16)f0.z, (__bf16)f0.w,
                 (__bf16)f1.x, (__bf16)f1.y, (__bf16)f1.z, (__bf16)f1.w };
    *(bf16x8*)&xb[i] = h;
}

// ---------------------------------------------------------------------------
// GEMM1: Y[t, n] = sum_k xb[t,k] * PiCat[n,k]
// ---------------------------------------------------------------------------
__global__ __launch_bounds__(256, 2) void gemm1_kernel(
    const __bf16* __restrict__ xb, const float* __restrict__ Pi,
    const float* __restrict__ Pi2, __bf16* __restrict__ Y)
{
    __shared__ __bf16 sA[2][128 * 64];   // 16KB each
    __shared__ __bf16 sB[2][64 * 64];    // 8KB each

    const int tid = threadIdx.x;
    const int n0  = blockIdx.x * 64;     // rotation-row tile
    const int t0  = blockIdx.y * 128;    // token tile
    const float* Bsrc = (n0 < N_DIM) ? Pi : Pi2;
    const int nloc = n0 & (N_DIM - 1);

    const int wid = tid >> 6, lane = tid & 63;
    const int wr = (wid >> 1) * 64, wc = (wid & 1) * 32;
    const int lr = lane & 15, lg = lane >> 4;

    // A staging geometry (global side; LDS side is linear, HW adds lane*16)
    const int arow = wid * 8 + (lane >> 3);     // + c*32
    const int acol = (lane & 7) * 8;
    // B staging: 4 threads/row, 16 consecutive k-floats each
    const int sr = tid >> 2, sc = (tid & 3) * 16;

    f32x4 acc[4][2] = {};
    float4 rb[4];

    auto issueA = [&](int buf, int k0) {
        #pragma unroll
        for (int c = 0; c < 4; ++c)
            gload16(&xb[(size_t)(t0 + c * 32 + arow) * N_DIM + k0 + acol],
                    &sA[buf][c * 2048 + wid * 512]);
    };
    auto loadB = [&](int k0) {
        const float* bp = &Bsrc[(size_t)(nloc + sr) * N_DIM + k0 + sc];
        #pragma unroll
        for (int q = 0; q < 4; ++q) rb[q] = *(const float4*)(bp + q * 4);
    };
    auto writeB = [&](int buf) {
        #pragma unroll
        for (int h = 0; h < 2; ++h) {
            float4 f0 = rb[h * 2], f1 = rb[h * 2 + 1];
            bf16x8 v = { (__bf16)f0.x, (__bf16)f0.y, (__bf16)f0.z, (__bf16)f0.w,
                         (__bf16)f1.x, (__bf16)f1.y, (__bf16)f1.z, (__bf16)f1.w };
            *(bf16x8*)&sB[buf][sr * 64 + sc + h * 8] = v;
        }
    };

    loadB(0);
    issueA(0, 0);
    writeB(0);
    __syncthreads();

    int cur = 0;
    for (int k = 0; k < N_DIM / 64; ++k) {
        const int k0n = (k + 1) * 64;
        if (k0n < N_DIM) { loadB(k0n); issueA(cur ^ 1, k0n); }

        bf16x8 af[4][2], bfr[2][2];
        #pragma unroll
        for (int m = 0; m < 4; ++m)
            #pragma unroll
            for (int kh = 0; kh < 2; ++kh)
                af[m][kh] = *(const bf16x8*)&sA[cur][(wr + m * 16 + lr) * 64 + kh * 32 + lg * 8];
        #pragma unroll
        for (int n = 0; n < 2; ++n)
            #pragma unroll
            for (int kh = 0; kh < 2; ++kh)
                bfr[n][kh] = *(const bf16x8*)&sB[cur][(wc + n * 16 + lr) * 64 + kh * 32 + lg * 8];
        #pragma unroll
        for (int m = 0; m < 4; ++m)
            #pragma unroll
            for (int n = 0; n < 2; ++n)
                #pragma unroll
                for (int kh = 0; kh < 2; ++kh)
                    acc[m][n] = __builtin_amdgcn_mfma_f32_16x16x32_bf16(
                        af[m][kh], bfr[n][kh], acc[m][n], 0, 0, 0);

        if (k0n < N_DIM) writeB(cur ^ 1);
        __syncthreads();
        cur ^= 1;
    }

    // epilogue: C/D layout col=lane&15, row=(lane>>4)*4+e  [m89/m91]
    #pragma unroll
    for (int m = 0; m < 4; ++m)
        #pragma unroll
        for (int n = 0; n < 2; ++n)
            #pragma unroll
            for (int e = 0; e < 4; ++e)
                Y[(size_t)(t0 + wr + m * 16 + lg * 4 + e) * K2_DIM +
                  n0 + wc + n * 16 + lr] = (__bf16)acc[m][n][e];
}

// ---------------------------------------------------------------------------
// GEMM2: out[t, m] += sum_j Y[t, pass*4096+j] * Wpass[m,j]
// ---------------------------------------------------------------------------
__global__ __launch_bounds__(256, 2) void gemm2_kernel(
    const __bf16* __restrict__ Y,
    const int*   __restrict__ idx1, const float* __restrict__ wn1,
    const float* __restrict__ cb1,
    const int*   __restrict__ idx2, const float* __restrict__ wn2,
    const float* __restrict__ cb2,
    float* __restrict__ out)
{
    __shared__ __bf16 sA[2][128 * 64];
    __shared__ __bf16 sB[2][64 * 64];
    __shared__ float2 lut[256];          // byte -> (low-nibble, high-nibble) centroids

    const int tid  = threadIdx.x;
    const int m0   = blockIdx.x * 64;    // weight-row tile
    const int t0   = blockIdx.y * 128;   // token tile
    const int pass = blockIdx.z;

    const int*   idxp = pass ? idx2 : idx1;
    const float* wn   = pass ? wn2  : wn1;
    const float* cbg  = pass ? cb2  : cb1;

    {   // build pair-LUT (one entry per thread)
        float lo = cbg[tid & 15] * INV_SQRT_G;
        float hi = cbg[(tid >> 4) & 15] * INV_SQRT_G;
        lut[tid] = make_float2(lo, hi);
    }

    const int wid = tid >> 6, lane = tid & 63;
    const int wr = (wid >> 1) * 64, wc = (wid & 1) * 32;
    const int lr = lane & 15, lg = lane >> 4;

    const int arow = wid * 8 + (lane >> 3);
    const int acol = (lane & 7) * 8;
    const int sr = tid >> 2, s4 = tid & 3;

    f32x4 acc[4][2] = {};
    int4  wi[2];
    float wscale;

    auto issueA = [&](int buf, int kl) {
        #pragma unroll
        for (int c = 0; c < 4; ++c)
            gload16(&Y[(size_t)(t0 + c * 32 + arow) * K2_DIM + pass * N_DIM + kl + acol],
                    &sA[buf][c * 2048 + wid * 512]);
    };
    auto loadB = [&](int kl) {
        const int* ip = &idxp[(size_t)(m0 + sr) * (N_DIM / 2) + (kl >> 1) + s4 * 8];
        wi[0] = *(const int4*)ip;
        wi[1] = *(const int4*)(ip + 4);
        wscale = wn[(size_t)(m0 + sr) * 32 + (kl >> 7)];
    };
    auto writeB = [&](int buf) {
        #pragma unroll
        for (int h = 0; h < 2; ++h) {
            int4 v = wi[h];
            float2 p0 = lut[v.x & 255], p1 = lut[v.y & 255];
            float2 p2 = lut[v.z & 255], p3 = lut[v.w & 255];
            bf16x8 w = { (__bf16)(p0.x * wscale), (__bf16)(p0.y * wscale),
                         (__bf16)(p1.x * wscale), (__bf16)(p1.y * wscale),
                         (__bf16)(p2.x * wscale), (__bf16)(p2.y * wscale),
                         (__bf16)(p3.x * wscale), (__bf16)(p3.y * wscale) };
            *(bf16x8*)&sB[buf][sr * 64 + s4 * 16 + h * 8] = w;
        }
    };

    loadB(0);
    issueA(0, 0);
    __syncthreads();          // lut ready before writeB reads it
    writeB(0);
    __syncthreads();

    int cur = 0;
    for (int k = 0; k < N_DIM / 64; ++k) {
        const int kln = (k + 1) * 64;
        if (kln < N_DIM) { loadB(kln); issueA(cur ^ 1, kln); }

        bf16x8 af[4][2], bfr[2][2];
        #pragma unroll
        for (int m = 0; m < 4; ++m)
            #pragma unroll
            for (int kh = 0; kh < 2; ++kh)
                af[m][kh] = *(const bf16x8*)&sA[cur][(wr + m * 16 + lr) * 64 + kh * 32 + lg * 8];
        #pragma unroll
        for (int n = 0; n < 2; ++n)
            #pragma unroll
            for (int kh = 0; kh < 2; ++kh)
                bfr[n][kh] = *(const bf16x8*)&sB[cur][(wc + n * 16 + lr) * 64 + kh * 32 + lg * 8];
        #pragma unroll
        for (int m = 0; m < 4; ++m)
            #pragma unroll
            for (int n = 0; n < 2; ++n)
                #pragma unroll
                for (int kh = 0; kh < 2; ++kh)
                    acc[m][n] = __builtin_amdgcn_mfma_f32_16x16x32_bf16(
                        af[m][kh], bfr[n][kh], acc[m][n], 0, 0, 0);

        if (kln < N_DIM) writeB(cur ^ 1);
        __syncthreads();
        cur ^= 1;
    }

    #pragma unroll
    for (int m = 0; m < 4; ++m)
        #pragma unroll
        for (int n = 0; n < 2; ++n)
            #pragma unroll
            for (int e = 0; e < 4; ++e)
                atomicAdd(&out[(size_t)(t0 + wr + m * 16 + lg * 4 + e) * M_DIM +
                               m0 + wc + n * 16 + lr], acc[m][n][e]);
}

// ---------------------------------------------------------------------------
extern "C" void kernel_launch(void* const* d_in, const int* in_sizes, int n_in,
                              void* d_out, int out_size, void* d_ws, size_t ws_size,
                              hipStream_t stream) {
    const float* x    = (const float*)d_in[0];
    const float* Pi   = (const float*)d_in[1];
    const int*   idx1 = (const int*)  d_in[2];
    const float* wn1  = (const float*)d_in[3];
    const float* cb1  = (const float*)d_in[4];
    const int*   idx2 = (const int*)  d_in[5];
    const float* wn2  = (const float*)d_in[6];
    const float* cb2  = (const float*)d_in[7];
    const float* Pi2  = (const float*)d_in[8];
    float* out = (float*)d_out;

    // ws layout: xb (512x4096 bf16 = 4MB) | Y (512x8192 bf16 = 8MB)
    __bf16* xb = (__bf16*)d_ws;
    __bf16* Yw = (__bf16*)((char*)d_ws + (size_t)T_DIM * N_DIM * sizeof(__bf16));

    hipMemsetAsync(d_out, 0, (size_t)T_DIM * M_DIM * sizeof(float), stream);

    cvt_x_kernel<<<dim3(T_DIM * N_DIM / (256 * 8)), dim3(256), 0, stream>>>(x, xb);
    gemm1_kernel<<<dim3(K2_DIM / 64, T_DIM / 128), dim3(256), 0, stream>>>(xb, Pi, Pi2, Yw);
    gemm2_kernel<<<dim3(M_DIM / 64, T_DIM / 128, 2), dim3(256), 0, stream>>>(
        Yw, idx1, wn1, cb1, idx2, wn2, cb2, out);
}

// Round 4
// 379.254 us; speedup vs baseline: 1.3772x; 1.0200x over previous
//
#include <hip/hip_runtime.h>
#include <hip/hip_bf16.h>

// Decomposition (split-K for occupancy; token dim is only 512):
//   xb  (512x4096 bf16, ws+0)    = cvt(x)
//   Y32 (512x8192 f32,  ws+4MB) += xb @ [Pi; Pi2]^T   (z=4 K-chunks, atomic f32)
//   Y   (512x8192 bf16, ws+20MB) = cvt(Y32)
//   out (512x4096 f32)          += Y @ Wpass^T        (z=8: 2 passes x 4 K-chunks, atomic)
// GEMM tile: 128x128, BK=32, 4 waves (2x2), wave-tile 64x64, acc 4x4,
// double-buffered LDS (32KB), A via global_load_lds(16B) linear
// (64B rows -> b128 frag reads at the 32-bank floor), B reg-staged with
// 16B-unit XOR swizzle (unit ^= row&3) so ds_writes also hit the floor.

typedef __bf16 bf16x8 __attribute__((ext_vector_type(8)));
typedef float  f32x4  __attribute__((ext_vector_type(4)));

#define T_DIM   512
#define N_DIM   4096
#define M_DIM   4096
#define K2_DIM  8192
#define INV_SQRT_G 0.08838834764831843f   // 1/sqrt(128)

typedef const __attribute__((address_space(1))) unsigned int as1_u32;
typedef __attribute__((address_space(3)))       unsigned int as3_u32;

__device__ __forceinline__ void gload16(const void* g, void* l) {
    // per-lane global src; LDS dst = wave-uniform base + lane*16 (m104)
    __builtin_amdgcn_global_load_lds((as1_u32*)g, (as3_u32*)l, 16, 0, 0);
}

// ---------------------------------------------------------------------------
__global__ __launch_bounds__(256) void cvt_x_kernel(
    const float* __restrict__ x, __bf16* __restrict__ xb)
{
    int i = (blockIdx.x * 256 + threadIdx.x) * 8;
    float4 f0 = *(const float4*)&x[i];
    float4 f1 = *(const float4*)&x[i + 4];
    bf16x8 h = { (__bf16)f0.x, (__bf16)f0.y, (__bf16)f0.z, (__bf16)f0.w,
                 (__bf16)f1.x, (__bf16)f1.y, (__bf16)f1.z, (__bf16)f1.w };
    *(bf16x8*)&xb[i] = h;
}

__global__ __launch_bounds__(256) void cvt_y_kernel(
    const float* __restrict__ Y32, __bf16* __restrict__ Y)
{
    int i = (blockIdx.x * 256 + threadIdx.x) * 8;
    float4 f0 = *(const float4*)&Y32[i];
    float4 f1 = *(const float4*)&Y32[i + 4];
    bf16x8 h = { (__bf16)f0.x, (__bf16)f0.y, (__bf16)f0.z, (__bf16)f0.w,
                 (__bf16)f1.x, (__bf16)f1.y, (__bf16)f1.z, (__bf16)f1.w };
    *(bf16x8*)&Y[i] = h;
}

// ---------------------------------------------------------------------------
// GEMM1: Y[t,n] (+)= sum_k xb[t,k] * PiCat[n,k] over this block's K-chunk.
// ---------------------------------------------------------------------------
template<bool SPLITK>
__global__ __launch_bounds__(256, 3) void gemm1_kernel(
    const __bf16* __restrict__ xb, const float* __restrict__ Pi,
    const float* __restrict__ Pi2, float* __restrict__ Y32,
    __bf16* __restrict__ Y)
{
    __shared__ __bf16 sA[2][128 * 32];   // 8KB each
    __shared__ __bf16 sB[2][128 * 32];

    const int tid   = threadIdx.x;
    const int n0    = blockIdx.x * 128;                 // rotation-row tile
    const int t0    = blockIdx.y * 128;                 // token tile
    const int kbase = blockIdx.z * (SPLITK ? 1024 : N_DIM);
    const int NK    = (SPLITK ? 1024 : N_DIM) / 32;

    const float* Bsrc = (n0 < N_DIM) ? Pi : Pi2;
    const int nloc = n0 & (N_DIM - 1);

    const int wid = tid >> 6, lane = tid & 63;
    const int wr = (wid >> 1) * 64, wc = (wid & 1) * 64;
    const int lr = lane & 15, lg = lane >> 4;
    const int sw = lr & 3;                               // B read swizzle bits

    // A staging: wave covers 16 rows x 4x16B units; c=0,1 -> +64 rows
    const int arow = wid * 16 + (lane >> 2);
    const int acol = (lane & 3) * 8;
    // B staging (fp32): 2 threads per row, 16 floats each
    const int br = tid >> 1, bh = tid & 1;

    f32x4 acc[4][4] = {};
    float4 rb[4];

    auto issueA = [&](int buf, int k0) {
        #pragma unroll
        for (int c = 0; c < 2; ++c)
            gload16(&xb[(size_t)(t0 + c * 64 + arow) * N_DIM + k0 + acol],
                    &sA[buf][(c * 64 + wid * 16) * 32]);
    };
    auto loadB = [&](int k0) {
        const float* bp = &Bsrc[(size_t)(nloc + br) * N_DIM + k0 + bh * 16];
        #pragma unroll
        for (int q = 0; q < 4; ++q) rb[q] = *(const float4*)(bp + q * 4);
    };
    auto writeB = [&](int buf) {
        #pragma unroll
        for (int h = 0; h < 2; ++h) {
            float4 f0 = rb[h * 2], f1 = rb[h * 2 + 1];
            bf16x8 v = { (__bf16)f0.x, (__bf16)f0.y, (__bf16)f0.z, (__bf16)f0.w,
                         (__bf16)f1.x, (__bf16)f1.y, (__bf16)f1.z, (__bf16)f1.w };
            int unit = (bh * 2 + h) ^ (br & 3);
            *(bf16x8*)&sB[buf][br * 32 + unit * 8] = v;
        }
    };

    loadB(kbase);
    issueA(0, kbase);
    writeB(0);
    __syncthreads();

    int cur = 0;
    for (int k = 0; k < NK; ++k) {
        const int kn = kbase + (k + 1) * 32;
        if (k + 1 < NK) { loadB(kn); issueA(cur ^ 1, kn); }

        bf16x8 af[4], bf[4];
        #pragma unroll
        for (int m = 0; m < 4; ++m)
            af[m] = *(const bf16x8*)&sA[cur][(wr + m * 16 + lr) * 32 + lg * 8];
        #pragma unroll
        for (int n = 0; n < 4; ++n)
            bf[n] = *(const bf16x8*)&sB[cur][(wc + n * 16 + lr) * 32 + (lg ^ sw) * 8];
        #pragma unroll
        for (int m = 0; m < 4; ++m)
            #pragma unroll
            for (int n = 0; n < 4; ++n)
                acc[m][n] = __builtin_amdgcn_mfma_f32_16x16x32_bf16(
                    af[m], bf[n], acc[m][n], 0, 0, 0);

        if (k + 1 < NK) writeB(cur ^ 1);
        __syncthreads();
        cur ^= 1;
    }

    // epilogue: C/D layout col=lane&15, row=(lane>>4)*4+e  [m89/m91]
    #pragma unroll
    for (int m = 0; m < 4; ++m)
        #pragma unroll
        for (int n = 0; n < 4; ++n)
            #pragma unroll
            for (int e = 0; e < 4; ++e) {
                size_t off = (size_t)(t0 + wr + m * 16 + lg * 4 + e) * K2_DIM +
                             n0 + wc + n * 16 + lr;
                if (SPLITK) unsafeAtomicAdd(&Y32[off], acc[m][n][e]);
                else        Y[off] = (__bf16)acc[m][n][e];
            }
}

// ---------------------------------------------------------------------------
// GEMM2: out[t,m] += sum_j Y[t, pass*4096+j] * Wpass[m,j] over K-chunk.
// z = 0..7: pass = z>>2, chunk = z&3 (K=1024 each).
// ---------------------------------------------------------------------------
__global__ __launch_bounds__(256, 3) void gemm2_kernel(
    const __bf16* __restrict__ Y,
    const int*   __restrict__ idx1, const float* __restrict__ wn1,
    const float* __restrict__ cb1,
    const int*   __restrict__ idx2, const float* __restrict__ wn2,
    const float* __restrict__ cb2,
    float* __restrict__ out)
{
    __shared__ __bf16 sA[2][128 * 32];
    __shared__ __bf16 sB[2][128 * 32];
    __shared__ float2 lut[256];          // byte -> (lo-nibble, hi-nibble)*INV_SQRT_G

    const int tid  = threadIdx.x;
    const int m0   = blockIdx.x * 128;   // weight-row tile
    const int t0   = blockIdx.y * 128;   // token tile
    const int pass = blockIdx.z >> 2;
    const int kof  = (blockIdx.z & 3) * 1024;   // pass-local K chunk base

    const int*   idxp = pass ? idx2 : idx1;
    const float* wn   = pass ? wn2  : wn1;
    const float* cbg  = pass ? cb2  : cb1;

    lut[tid] = make_float2(cbg[tid & 15] * INV_SQRT_G,
                           cbg[(tid >> 4) & 15] * INV_SQRT_G);

    const int wid = tid >> 6, lane = tid & 63;
    const int wr = (wid >> 1) * 64, wc = (wid & 1) * 64;
    const int lr = lane & 15, lg = lane >> 4;
    const int sw = lr & 3;

    const int arow = wid * 16 + (lane >> 2);
    const int acol = (lane & 3) * 8;
    const int br = tid >> 1, bh = tid & 1;    // B: 2 threads/row, 8 int32 each

    f32x4 acc[4][4] = {};
    int4  wi[2];
    float wscale;

    auto issueA = [&](int buf, int kl) {      // kl = pass-local k offset
        #pragma unroll
        for (int c = 0; c < 2; ++c)
            gload16(&Y[(size_t)(t0 + c * 64 + arow) * K2_DIM + pass * N_DIM + kl + acol],
                    &sA[buf][(c * 64 + wid * 16) * 32]);
    };
    auto loadB = [&](int kl) {
        const int* ip = &idxp[(size_t)(m0 + br) * (N_DIM / 2) + (kl >> 1) + bh * 8];
        wi[0] = *(const int4*)ip;
        wi[1] = *(const int4*)(ip + 4);
        wscale = wn[(size_t)(m0 + br) * 32 + (kl >> 7)];
    };
    auto writeB = [&](int buf) {
        #pragma unroll
        for (int h = 0; h < 2; ++h) {
            int4 v = wi[h];
            float2 p0 = lut[v.x & 255], p1 = lut[v.y & 255];
            float2 p2 = lut[v.z & 255], p3 = lut[v.w & 255];
            bf16x8 w = { (__bf16)(p0.x * wscale), (__bf16)(p0.y * wscale),
                         (__bf16)(p1.x * wscale), (__bf16)(p1.y * wscale),
                         (__bf16)(p2.x * wscale), (__bf16)(p2.y * wscale),
                         (__bf16)(p3.x * wscale), (__bf16)(p3.y * wscale) };
            int unit = (bh * 2 + h) ^ (br & 3);
            *(bf16x8*)&sB[buf][br * 32 + unit * 8] = w;
        }
    };

    loadB(kof);
    issueA(0, kof);
    __syncthreads();          // lut ready (and first gloads drained per-wave)
    writeB(0);
    __syncthreads();

    int cur = 0;
    const int NK = 1024 / 32;
    for (int k = 0; k < NK; ++k) {
        const int kn = kof + (k + 1) * 32;
        if (k + 1 < NK) { loadB(kn); issueA(cur ^ 1, kn); }

        bf16x8 af[4], bf[4];
        #pragma unroll
        for (int m = 0; m < 4; ++m)
            af[m] = *(const bf16x8*)&sA[cur][(wr + m * 16 + lr) * 32 + lg * 8];
        #pragma unroll
        for (int n = 0; n < 4; ++n)
            bf[n] = *(const bf16x8*)&sB[cur][(wc + n * 16 + lr) * 32 + (lg ^ sw) * 8];
        #pragma unroll
        for (int m = 0; m < 4; ++m)
            #pragma unroll
            for (int n = 0; n < 4; ++n)
                acc[m][n] = __builtin_amdgcn_mfma_f32_16x16x32_bf16(
                    af[m], bf[n], acc[m][n], 0, 0, 0);

        if (k + 1 < NK) writeB(cur ^ 1);
        __syncthreads();
        cur ^= 1;
    }

    #pragma unroll
    for (int m = 0; m < 4; ++m)
        #pragma unroll
        for (int n = 0; n < 4; ++n)
            #pragma unroll
            for (int e = 0; e < 4; ++e)
                unsafeAtomicAdd(&out[(size_t)(t0 + wr + m * 16 + lg * 4 + e) * M_DIM +
                                     m0 + wc + n * 16 + lr], acc[m][n][e]);
}

// ---------------------------------------------------------------------------
extern "C" void kernel_launch(void* const* d_in, const int* in_sizes, int n_in,
                              void* d_out, int out_size, void* d_ws, size_t ws_size,
                              hipStream_t stream) {
    const float* x    = (const float*)d_in[0];
    const float* Pi   = (const float*)d_in[1];
    const int*   idx1 = (const int*)  d_in[2];
    const float* wn1  = (const float*)d_in[3];
    const float* cb1  = (const float*)d_in[4];
    const int*   idx2 = (const int*)  d_in[5];
    const float* wn2  = (const float*)d_in[6];
    const float* cb2  = (const float*)d_in[7];
    const float* Pi2  = (const float*)d_in[8];
    float* out = (float*)d_out;

    const size_t xb_bytes  = (size_t)T_DIM * N_DIM * sizeof(__bf16);   // 4MB
    const size_t y32_bytes = (size_t)T_DIM * K2_DIM * sizeof(float);   // 16MB
    const size_t y_bytes   = (size_t)T_DIM * K2_DIM * sizeof(__bf16);  // 8MB
    const bool   splitk    = ws_size >= xb_bytes + y32_bytes + y_bytes;

    __bf16* xb  = (__bf16*)d_ws;
    float*  Y32 = (float*)((char*)d_ws + xb_bytes);
    __bf16* Yb  = splitk ? (__bf16*)((char*)d_ws + xb_bytes + y32_bytes)
                         : (__bf16*)((char*)d_ws + xb_bytes);

    hipMemsetAsync(out, 0, (size_t)T_DIM * M_DIM * sizeof(float), stream);
    cvt_x_kernel<<<dim3(T_DIM * N_DIM / (256 * 8)), dim3(256), 0, stream>>>(x, xb);

    if (splitk) {
        hipMemsetAsync(Y32, 0, y32_bytes, stream);
        gemm1_kernel<true><<<dim3(K2_DIM / 128, T_DIM / 128, 4), dim3(256), 0, stream>>>(
            xb, Pi, Pi2, Y32, Yb);
        cvt_y_kernel<<<dim3(T_DIM * K2_DIM / (256 * 8)), dim3(256), 0, stream>>>(Y32, Yb);
    } else {
        gemm1_kernel<false><<<dim3(K2_DIM / 128, T_DIM / 128, 1), dim3(256), 0, stream>>>(
            xb, Pi, Pi2, Y32, Yb);
    }

    gemm2_kernel<<<dim3(M_DIM / 128, T_DIM / 128, 8), dim3(256), 0, stream>>>(
        Yb, idx1, wn1, cb1, idx2, wn2, cb2, out);
}